// Round 2
// baseline (510.140 us; speedup 1.0000x reference)
//
#include <hip/hip_runtime.h>
#include <math.h>

#define N_LEAVES 65536
#define WAVES 24
#define WC 2048
#define KSPLITS 3
#define S 128
#define CTOT (N_LEAVES + WAVES * WC)   // 114688
#define N_INT (WAVES * WC)             // 49152 internal clades
#define G 2048
#define E_ITERS 50
#define EPS 1e-30f

#define NBLK 256
#define TPB 512   // 8 wavefronts per block; 256*8 = 2048 wavefronts = WC

// ---------------------------------------------------------------------------
// setup: zero the barrier counter and the output accumulator (must happen
// every call — counter is monotonic within one fused-kernel execution).
// ---------------------------------------------------------------------------
__global__ void setup_kernel(int* __restrict__ cnt, float* __restrict__ out) {
    if (threadIdx.x == 0) {
        cnt[0] = 0;
        out[0] = 0.0f;
    }
}

// ---------------------------------------------------------------------------
// grid barrier: monotonic counter, one arrival per block, agent-scope.
// Release fence flushes this XCD's L2 (P-row writes) to the die-level L3;
// acquire fence after the spin invalidates stale L1/L2 lines.
// ---------------------------------------------------------------------------
__device__ __forceinline__ void gbar(int* cnt, int target) {
    __syncthreads();
    if (threadIdx.x == 0) {
        __threadfence();  // release: push P/ls writes to coherence point
        __hip_atomic_fetch_add(cnt, 1, __ATOMIC_RELAXED, __HIP_MEMORY_SCOPE_AGENT);
        while (__hip_atomic_load(cnt, __ATOMIC_RELAXED, __HIP_MEMORY_SCOPE_AGENT) < target)
            __builtin_amdgcn_s_sleep(1);
        __threadfence();  // acquire: invalidate stale cached lines
    }
    __syncthreads();
}

// Classify + load one wave's 6 children for clade c into registers.
// leaf -> one-hot from species (sum=1); internal < LO_SAFE -> gather row
// (mark for sum-reduce); in [LO_SAFE, LO_CUR) -> defer until after barrier;
// >= LO_CUR -> statically zero (sum=0).
#define PREFETCH(KK, LO_SAFE, LO_CUR, PV, PS, WQ, PIDX, ROWM, DEFM)            \
  {                                                                            \
    const int base_ = ((KK) * WC + c) * KSPLITS;                               \
    float l0_ = logw[base_], l1_ = logw[base_ + 1], l2_ = logw[base_ + 2];     \
    float m_ = fmaxf(l0_, fmaxf(l1_, l2_));                                    \
    float e0_ = expf(l0_ - m_), e1_ = expf(l1_ - m_), e2_ = expf(l2_ - m_);    \
    float inv_ = 1.0f / (e0_ + e1_ + e2_);                                     \
    WQ[0] = e0_ * inv_; WQ[1] = e1_ * inv_; WQ[2] = e2_ * inv_;                \
    ROWM = 0; DEFM = 0;                                                        \
    _Pragma("unroll")                                                          \
    for (int j_ = 0; j_ < 6; ++j_) {                                           \
      int idx_ = (j_ < 3) ? left[base_ + j_] : right[base_ + j_ - 3];          \
      PIDX[j_] = idx_;                                                         \
      float2 v_ = make_float2(0.f, 0.f);                                       \
      float s_ = 0.f;                                                          \
      if (idx_ < N_LEAVES) {                                                   \
        int sp_ = leaf_species[idx_];                                          \
        v_.x = (sp_ == 2 * lane) ? 1.f : 0.f;                                  \
        v_.y = (sp_ == 2 * lane + 1) ? 1.f : 0.f;                              \
        s_ = 1.f;                                                              \
      } else if (idx_ < (LO_SAFE)) {                                           \
        v_ = *(const float2*)&P[(size_t)(idx_ - N_LEAVES) * S + 2 * lane];     \
        ROWM |= 1 << j_;                                                       \
      } else if (idx_ < (LO_CUR)) {                                            \
        DEFM |= 1 << j_;                                                       \
      }                                                                        \
      PV[j_] = v_; PS[j_] = s_;                                                \
    }                                                                          \
  }

// ---------------------------------------------------------------------------
// fused: all 24 waves + final reduce in one persistent kernel.
// 2048 wavefronts, wavefront w owns clade slot w of EVERY wave (so next-wave
// indices/softmax/old-row gathers are prefetchable during current compute).
// ---------------------------------------------------------------------------
__global__ __launch_bounds__(TPB, 2) void fused_kernel(
    const float* __restrict__ theta, const float* __restrict__ logw,
    const int* __restrict__ left, const int* __restrict__ right,
    const int* __restrict__ leaf_species, const int* __restrict__ root_ids,
    float* __restrict__ P, float* __restrict__ ls,
    int* __restrict__ cnt, float* __restrict__ out) {
    const int lane = threadIdx.x & 63;
    const int c = blockIdx.x * (TPB / 64) + (threadIdx.x >> 6);  // clade slot

    // DTL rates + extinction fixed point (e is uniform across species, so
    // mean(e) == e bitwise; scalar iteration, redundantly per-thread).
    const float D = exp2f(theta[0]);
    const float L = exp2f(theta[1]);
    const float T = exp2f(theta[2]);
    const float norm = D + L + T + 1.0f;
    float e = L / norm;
#pragma unroll 1
    for (int i = 0; i < E_ITERS; ++i)
        e = (L + D * e * e + T * e * e) / norm;
    const float denom = 1.0f + D * e + T * e;
    const float onepD = 1.0f + D;
    const float T127 = T / 127.0f;

    // current-wave child state
    float2 pv[6]; float ps[6]; float wq[3]; int pidx[6]; int rowm, defm;
    // next-wave child state
    float2 npv[6]; float nps[6]; float nwq[3]; int nidx[6]; int nrowm, ndefm;

    PREFETCH(0, N_LEAVES, N_LEAVES, pv, ps, wq, pidx, rowm, defm);

    for (int k = 0; k < WAVES; ++k) {
        if (k) gbar(cnt, NBLK * k);  // wave k-1 rows now visible
        const int lo_cur = N_LEAVES + k * WC;

        // deferred gathers: children written by wave k-1
        if (defm) {
#pragma unroll
            for (int j = 0; j < 6; ++j)
                if ((defm >> j) & 1)
                    pv[j] = *(const float2*)&P[(size_t)(pidx[j] - N_LEAVES) * S + 2 * lane];
            rowm |= defm;
        }

        // prefetch wave k+1 (indices static; rows < lo_k already final)
        if (k < WAVES - 1)
            PREFETCH(k + 1, lo_cur, lo_cur + WC, npv, nps, nwq, nidx, nrowm, ndefm);

        // row sums (only gathered rows need the shuffle reduce)
        float ssum[6];
#pragma unroll
        for (int j = 0; j < 6; ++j) {
            float s = ps[j];
            if ((rowm >> j) & 1) {
                s = pv[j].x + pv[j].y;
#pragma unroll
                for (int d = 1; d < 64; d <<= 1)
                    s += __shfl_xor(s, d);
            }
            ssum[j] = s;
        }

        float v0 = 0.f, v1 = 0.f;
#pragma unroll
        for (int jj = 0; jj < KSPLITS; ++jj) {
            float2 a = pv[jj], b = pv[jj + 3];
            float sl = ssum[jj], sr = ssum[jj + 3], w = wq[jj];
            v0 += w * (onepD * a.x * b.x + T127 * (a.x * (sr - b.x) + b.x * (sl - a.x)));
            v1 += w * (onepD * a.y * b.y + T127 * (a.y * (sr - b.y) + b.y * (sl - a.y)));
        }
        v0 /= denom;
        v1 /= denom;

        float mx = fmaxf(v0, v1);
#pragma unroll
        for (int d = 1; d < 64; d <<= 1)
            mx = fmaxf(mx, __shfl_xor(mx, d));
        const float safe = fmaxf(mx, EPS);

        const int row = k * WC + c;
        *(float2*)&P[(size_t)row * S + 2 * lane] = make_float2(v0 / safe, v1 / safe);
        if (lane == 0)
            ls[row] = logf(safe);

        // rotate next -> current
#pragma unroll
        for (int j = 0; j < 6; ++j) { pv[j] = npv[j]; ps[j] = nps[j]; pidx[j] = nidx[j]; }
        wq[0] = nwq[0]; wq[1] = nwq[1]; wq[2] = nwq[2];
        rowm = nrowm; defm = ndefm;
    }

    gbar(cnt, NBLK * WAVES);  // all waves final

    // final: one family per wavefront. Leaf roots contribute exactly 0
    // (log(1+1e-30)==0 in f32, ls==0) — skipped bitwise-exactly.
    const int r = root_ids[c];
    if (r >= N_LEAVES) {
        const int row = r - N_LEAVES;
        float2 p = *(const float2*)&P[(size_t)row * S + 2 * lane];
        float s = p.x + p.y;
#pragma unroll
        for (int d = 1; d < 64; d <<= 1)
            s += __shfl_xor(s, d);
        if (lane == 0)
            atomicAdd(out, -(logf(s + EPS) + ls[row]));
    }
}

// ---------------------------------------------------------------------------
extern "C" void kernel_launch(void* const* d_in, const int* in_sizes, int n_in,
                              void* d_out, int out_size, void* d_ws, size_t ws_size,
                              hipStream_t stream) {
    const float* theta        = (const float*)d_in[0];
    const float* logw         = (const float*)d_in[1];
    const int*   left         = (const int*)d_in[2];
    const int*   right        = (const int*)d_in[3];
    const int*   leaf_species = (const int*)d_in[4];
    const int*   root_ids     = (const int*)d_in[5];
    float* out = (float*)d_out;

    char* ws = (char*)d_ws;
    int*   cnt = (int*)ws;                                      // barrier counter
    float* P   = (float*)(ws + 256);                            // internal rows only: 49152*128*4 = 25.17 MB
    float* ls  = (float*)(ws + 256 + (size_t)N_INT * S * 4);    // 49152*4

    setup_kernel<<<1, 64, 0, stream>>>(cnt, out);
    fused_kernel<<<NBLK, TPB, 0, stream>>>(theta, logw, left, right,
                                           leaf_species, root_ids, P, ls, cnt, out);
}

// Round 3
// 117.473 us; speedup vs baseline: 4.3426x; 4.3426x over previous
//
#include <hip/hip_runtime.h>
#include <math.h>

#define N_LEAVES 65536
#define WAVES 24
#define WC 2048
#define KSPLITS 3
#define S 128
#define N_INT (WAVES * WC)   // 49152 internal clades
#define G 2048
#define E_ITERS 50
#define EPS 1e-30f

#define NBLK 256
#define TPB 512   // 8 wavefronts/block; 256*8 = 2048 wavefronts = one per clade slot

#define AGENT __HIP_MEMORY_SCOPE_AGENT

// ---------------------------------------------------------------------------
// zero: flags + output accumulator. Normal stores — flushed to memory at
// end-of-dispatch (system-scope release), so the fused kernel's sc1 (L2-
// bypassing) reads see them. Runs every call (flags are monotone per call).
// ---------------------------------------------------------------------------
__global__ void zero_kernel(int* __restrict__ flags, float* __restrict__ out) {
    int i = blockIdx.x * blockDim.x + threadIdx.x;
    if (i < N_INT) flags[i] = 0;
    if (i == 0) out[0] = 0.0f;
}

union F2U { float2 f; unsigned long long u; };

// agent-scope (sc1, IF-coherent) 8B row-fragment load; `dep` carries a data
// dependency on the observed flag value so the gather cannot be hoisted
// above the flag observation by compiler or hardware.
__device__ __forceinline__ float2 row_gather(const float* __restrict__ P,
                                             int row, int lane, int dep) {
    const unsigned long long* p =
        (const unsigned long long*)(P + (size_t)row * S) + (lane + dep);
    F2U x;
    x.u = __hip_atomic_load(p, __ATOMIC_RELAXED, AGENT);
    return x.f;
}

// Classify + load children of wave KK's clade c.
// leaf -> one-hot (sum=1); idx >= wave-KK start -> statically zero (sum=0,
// matches reference reading the pre-wave carry); else internal-past:
// flag set -> gather now (ROWM), unset -> pend (resolved by poll later).
#define PREFETCH(KK, PV, PS, WQ, PIDX, ROWM, PEND)                             \
  {                                                                            \
    const int lo_ = N_LEAVES + (KK) * WC;                                      \
    const int base_ = ((KK) * WC + c) * KSPLITS;                               \
    float l0_ = logw[base_], l1_ = logw[base_ + 1], l2_ = logw[base_ + 2];     \
    float m_ = fmaxf(l0_, fmaxf(l1_, l2_));                                    \
    float e0_ = expf(l0_ - m_), e1_ = expf(l1_ - m_), e2_ = expf(l2_ - m_);    \
    float inv_ = 1.0f / (e0_ + e1_ + e2_);                                     \
    WQ[0] = e0_ * inv_; WQ[1] = e1_ * inv_; WQ[2] = e2_ * inv_;                \
    ROWM = 0; PEND = 0;                                                        \
    _Pragma("unroll")                                                          \
    for (int j_ = 0; j_ < 6; ++j_) {                                           \
      int idx_ = (j_ < 3) ? left[base_ + j_] : right[base_ + j_ - 3];          \
      PIDX[j_] = idx_;                                                         \
      float2 v_ = make_float2(0.f, 0.f);                                       \
      float s_ = 0.f;                                                          \
      if (idx_ < N_LEAVES) {                                                   \
        int sp_ = leaf_species[idx_];                                          \
        v_.x = (sp_ == 2 * lane) ? 1.f : 0.f;                                  \
        v_.y = (sp_ == 2 * lane + 1) ? 1.f : 0.f;                              \
        s_ = 1.f;                                                              \
      } else if (idx_ < lo_) {                                                 \
        int r_ = idx_ - N_LEAVES;                                              \
        int f_ = __hip_atomic_load(&flags[r_], __ATOMIC_RELAXED, AGENT);       \
        if (f_) {                                                              \
          v_ = row_gather(P, r_, lane, (int)((unsigned)f_ >> 31));             \
          ROWM |= 1 << j_;                                                     \
        } else {                                                               \
          PEND |= 1 << j_;                                                     \
        }                                                                      \
      }                                                                        \
      PV[j_] = v_; PS[j_] = s_;                                                \
    }                                                                          \
  }

// ---------------------------------------------------------------------------
// fused: all 24 waves + final reduce, NO global barriers — per-row dataflow
// flags. All P/ls/flag traffic is relaxed agent-scope (sc1 -> coherent at
// the memory-side Infinity Cache); read-only inputs stay L1/L2-cached.
// ---------------------------------------------------------------------------
__global__ __launch_bounds__(TPB, 2) void fused_kernel(
    const float* __restrict__ theta, const float* __restrict__ logw,
    const int* __restrict__ left, const int* __restrict__ right,
    const int* __restrict__ leaf_species, const int* __restrict__ root_ids,
    float* __restrict__ P, float* __restrict__ ls,
    int* __restrict__ flags, float* __restrict__ out) {
    const int lane = threadIdx.x & 63;
    const int c = blockIdx.x * (TPB / 64) + (threadIdx.x >> 6);  // clade slot

    // DTL rates + extinction fixed point (e uniform across species ->
    // mean(e) == e bitwise; scalar iteration).
    const float D = exp2f(theta[0]);
    const float L = exp2f(theta[1]);
    const float T = exp2f(theta[2]);
    const float norm = D + L + T + 1.0f;
    float e = L / norm;
#pragma unroll 1
    for (int i = 0; i < E_ITERS; ++i)
        e = (L + D * e * e + T * e * e) / norm;
    const float denom = 1.0f + D * e + T * e;
    const float onepD = 1.0f + D;
    const float T127 = T / 127.0f;

    float2 pv[6]; float ps[6]; float wq[3]; int pidx[6]; int rowm, pend;
    float2 npv[6]; float nps[6]; float nwq[3]; int nidx[6]; int nrowm, npend;

    PREFETCH(0, pv, ps, wq, pidx, rowm, pend);  // wave 0: no gathers possible

    for (int k = 0; k < WAVES; ++k) {
        // 1. resolve still-pending children (rows finalize monotonically)
        while (pend) {
            int got = 0;
#pragma unroll
            for (int j = 0; j < 6; ++j)
                if ((pend >> j) & 1) {
                    int r = pidx[j] - N_LEAVES;
                    int f = __hip_atomic_load(&flags[r], __ATOMIC_RELAXED, AGENT);
                    if (f) {
                        pv[j] = row_gather(P, r, lane, (int)((unsigned)f >> 31));
                        got |= 1 << j;
                    }
                }
            rowm |= got;
            pend &= ~got;
            if (pend) __builtin_amdgcn_s_sleep(2);
        }

        // 2. row sums (shuffle reduce only for gathered rows)
        float ssum[6];
#pragma unroll
        for (int j = 0; j < 6; ++j) {
            float s = ps[j];
            if ((rowm >> j) & 1) {
                s = pv[j].x + pv[j].y;
#pragma unroll
                for (int d = 1; d < 64; d <<= 1)
                    s += __shfl_xor(s, d);
            }
            ssum[j] = s;
        }

        // 3. clade likelihood row
        float v0 = 0.f, v1 = 0.f;
#pragma unroll
        for (int jj = 0; jj < KSPLITS; ++jj) {
            float2 a = pv[jj], b = pv[jj + 3];
            float sl = ssum[jj], sr = ssum[jj + 3], w = wq[jj];
            v0 += w * (onepD * a.x * b.x + T127 * (a.x * (sr - b.x) + b.x * (sl - a.x)));
            v1 += w * (onepD * a.y * b.y + T127 * (a.y * (sr - b.y) + b.y * (sl - a.y)));
        }
        v0 /= denom;
        v1 /= denom;

        float mx = fmaxf(v0, v1);
#pragma unroll
        for (int d = 1; d < 64; d <<= 1)
            mx = fmaxf(mx, __shfl_xor(mx, d));
        const float safe = fmaxf(mx, EPS);

        // 4. publish: row + ls (sc1) -> drain to coherence point -> flag
        const int row = k * WC + c;
        F2U o;
        o.f = make_float2(v0 / safe, v1 / safe);
        __hip_atomic_store((unsigned long long*)(P + (size_t)row * S) + lane,
                           o.u, __ATOMIC_RELAXED, AGENT);
        if (lane == 0)
            __hip_atomic_store(&ls[row], logf(safe), __ATOMIC_RELAXED, AGENT);
        asm volatile("s_waitcnt vmcnt(0)" ::: "memory");
        if (lane == 0)
            __hip_atomic_store(&flags[row], 1, __ATOMIC_RELAXED, AGENT);

        // 5. prefetch wave k+1 (indices/softmax/leaf one-hots + early gathers
        //    of already-flagged children, overlapping the next poll/compute)
        if (k < WAVES - 1) {
            PREFETCH(k + 1, npv, nps, nwq, nidx, nrowm, npend);
#pragma unroll
            for (int j = 0; j < 6; ++j) {
                pv[j] = npv[j]; ps[j] = nps[j]; pidx[j] = nidx[j];
            }
            wq[0] = nwq[0]; wq[1] = nwq[1]; wq[2] = nwq[2];
            rowm = nrowm; pend = npend;
        }
    }

    // final: one family per wavefront. Leaf roots contribute exactly 0
    // (log(1) + 0) — skipped bitwise-exactly.
    const int r = root_ids[c];
    if (r >= N_LEAVES) {
        const int row = r - N_LEAVES;
        int f;
        while (!(f = __hip_atomic_load(&flags[row], __ATOMIC_RELAXED, AGENT)))
            __builtin_amdgcn_s_sleep(2);
        float2 p = row_gather(P, row, lane, (int)((unsigned)f >> 31));
        float s = p.x + p.y;
#pragma unroll
        for (int d = 1; d < 64; d <<= 1)
            s += __shfl_xor(s, d);
        if (lane == 0) {
            float lsv = __hip_atomic_load(&ls[row + (int)((unsigned)f >> 31)],
                                          __ATOMIC_RELAXED, AGENT);
            atomicAdd(out, -(logf(s + EPS) + lsv));  // device-scope by default
        }
    }
}

// ---------------------------------------------------------------------------
extern "C" void kernel_launch(void* const* d_in, const int* in_sizes, int n_in,
                              void* d_out, int out_size, void* d_ws, size_t ws_size,
                              hipStream_t stream) {
    const float* theta        = (const float*)d_in[0];
    const float* logw         = (const float*)d_in[1];
    const int*   left         = (const int*)d_in[2];
    const int*   right        = (const int*)d_in[3];
    const int*   leaf_species = (const int*)d_in[4];
    const int*   root_ids     = (const int*)d_in[5];
    float* out = (float*)d_out;

    char* ws = (char*)d_ws;
    int*   flags = (int*)ws;                                     // N_INT ints
    float* P     = (float*)(ws + ((size_t)N_INT * 4 + 255 & ~255ull));
    float* ls    = (float*)((char*)P + (size_t)N_INT * S * 4);   // N_INT floats

    zero_kernel<<<(N_INT + TPB - 1) / TPB, TPB, 0, stream>>>(flags, out);
    fused_kernel<<<NBLK, TPB, 0, stream>>>(theta, logw, left, right,
                                           leaf_species, root_ids, P, ls,
                                           flags, out);
}

// Round 4
// 89.340 us; speedup vs baseline: 5.7101x; 1.3149x over previous
//
#include <hip/hip_runtime.h>
#include <math.h>

#define N_LEAVES 65536
#define WAVES 24
#define WC 2048
#define KSPLITS 3
#define S 128
#define N_INT (WAVES * WC)   // 49152 internal clades
#define G 2048
#define E_ITERS 50
#define EPS 1e-30f

#define NBLK 256
#define TPB 512   // 8 wavefronts/block; 256*8 = 2048 wavefronts = one per clade slot

#define AGENT __HIP_MEMORY_SCOPE_AGENT
#define SENT8 0xFFFFFFFFFFFFFFFFull
#define SENT4 0xFFFFFFFFu

union F2U { float2 f; unsigned long long u; };

// ---------------------------------------------------------------------------
// init: sentinel-fill P (25.2 MB), rsum, ls; zero out. Plain stores — the
// end-of-dispatch writeback makes them visible to the fused kernel's sc1
// (L2-bypassing) accesses. P values are probabilities in [0,1] and rsum/ls
// are finite reals, so the all-ones (NaN) pattern can never be produced by
// real data: the data itself is the ready flag.
// ---------------------------------------------------------------------------
__global__ __launch_bounds__(256) void init_kernel(uint4* __restrict__ P4,
                                                   unsigned* __restrict__ rsum,
                                                   unsigned* __restrict__ lsu,
                                                   float* __restrict__ out) {
    const int NP4 = N_INT * S / 4;   // 1,572,864 uint4
    int idx = blockIdx.x * 256 + threadIdx.x;
    int stride = gridDim.x * 256;
    uint4 s4 = make_uint4(SENT4, SENT4, SENT4, SENT4);
    for (int i = idx; i < NP4; i += stride) P4[i] = s4;
    for (int i = idx; i < N_INT; i += stride) { rsum[i] = SENT4; lsu[i] = SENT4; }
    if (idx == 0) out[0] = 0.0f;
}

__device__ __forceinline__ unsigned long long frag_load(const float* __restrict__ P,
                                                        int r, int lane) {
    return __hip_atomic_load((const unsigned long long*)(P + (size_t)r * S) + lane,
                             __ATOMIC_RELAXED, AGENT);
}

// load 6 child indices + 3 split logits for wave KK (wave-uniform addresses)
#define ISSUE_IDX(KK, IDX, LWV)                                                \
  {                                                                            \
    const int b_ = ((KK) * WC + c) * KSPLITS;                                  \
    _Pragma("unroll")                                                          \
    for (int j_ = 0; j_ < 3; ++j_) {                                           \
      IDX[j_]     = left[b_ + j_];                                             \
      IDX[j_ + 3] = right[b_ + j_];                                            \
      LWV[j_]     = logw[b_ + j_];                                             \
    }                                                                          \
  }

// classify children of wave KK and ISSUE all loads (species, row fragments,
// row sums). No loaded value is consumed here — checks happen at resolve.
#define GATHER_CLASSIFY(KK, IDX, LWV, PV, RS, SP, PIDX, WQ, LEAFM, PEND)       \
  {                                                                            \
    const int lo_ = N_LEAVES + (KK) * WC;                                      \
    float m_ = fmaxf(LWV[0], fmaxf(LWV[1], LWV[2]));                           \
    float e0_ = expf(LWV[0] - m_), e1_ = expf(LWV[1] - m_),                    \
          e2_ = expf(LWV[2] - m_);                                             \
    float inv_ = 1.0f / (e0_ + e1_ + e2_);                                     \
    WQ[0] = e0_ * inv_; WQ[1] = e1_ * inv_; WQ[2] = e2_ * inv_;                \
    LEAFM = 0; PEND = 0;                                                       \
    _Pragma("unroll")                                                          \
    for (int j_ = 0; j_ < 6; ++j_) {                                           \
      int idx_ = IDX[j_];                                                      \
      PIDX[j_] = idx_;                                                         \
      float2 v_ = make_float2(0.f, 0.f);                                       \
      float rs_ = 0.f;                                                         \
      int sp_ = -1;                                                            \
      if (idx_ < N_LEAVES) {                                                   \
        LEAFM |= 1 << j_;                                                      \
        sp_ = leaf_species[idx_];                                              \
      } else if (idx_ < lo_) {                                                 \
        PEND |= 1 << j_;                                                       \
        int r_ = idx_ - N_LEAVES;                                              \
        F2U u_; u_.u = frag_load(P, r_, lane);                                 \
        v_ = u_.f;                                                             \
        rs_ = __hip_atomic_load(&rsum[r_], __ATOMIC_RELAXED, AGENT);           \
      }                                                                        \
      PV[j_] = v_; RS[j_] = rs_; SP[j_] = sp_;                                 \
    }                                                                          \
  }

// ---------------------------------------------------------------------------
// fused: all 24 waves + final reduce; per-fragment value-based dataflow.
// Publisher: sc1-store row fragments + rsum + ls, NO drain, NO flag.
// Consumer: poll own fragment / rsum word until != sentinel.
// ---------------------------------------------------------------------------
__global__ __launch_bounds__(TPB, 2) void fused_kernel(
    const float* __restrict__ theta, const float* __restrict__ logw,
    const int* __restrict__ left, const int* __restrict__ right,
    const int* __restrict__ leaf_species, const int* __restrict__ root_ids,
    float* __restrict__ P, float* __restrict__ rsum, float* __restrict__ lsv,
    float* __restrict__ out) {
    const int lane = threadIdx.x & 63;
    const int c = blockIdx.x * (TPB / 64) + (threadIdx.x >> 6);  // clade slot

    // DTL rates + extinction fixed point (e uniform across species ->
    // mean(e) == e bitwise; scalar iteration).
    const float D = exp2f(theta[0]);
    const float L = exp2f(theta[1]);
    const float T = exp2f(theta[2]);
    const float norm = D + L + T + 1.0f;
    float e = L / norm;
#pragma unroll 1
    for (int i = 0; i < E_ITERS; ++i)
        e = (L + D * e * e + T * e * e) / norm;
    const float denom = 1.0f + D * e + T * e;
    const float onepD = 1.0f + D;
    const float T127 = T / 127.0f;

    // current-wave child state (rs doubles as the per-child row sum:
    // gathered -> rsum value, leaf -> 1, future/current-wave -> 0)
    float2 pv[6]; float rs[6]; int sp6[6]; int pidx[6]; float wq[3];
    int leafm, pend;
    float2 npv[6]; float nrs[6]; int nsp[6]; int npidx[6]; float nwq[3];
    int nleafm, npend;

    int idxC[6]; float lwC[3];
    ISSUE_IDX(0, idxC, lwC);
    GATHER_CLASSIFY(0, idxC, lwC, pv, rs, sp6, pidx, wq, leafm, pend);
    // wave 0 children are leaves or zero -> pend == 0

    int idxT[6]; float lwT[3];

    for (int k = 0; k < WAVES; ++k) {
        // 1. issue next wave's index/logit loads (hide under resolve/compute)
        if (k + 1 < WAVES) ISSUE_IDX(k + 1, idxT, lwT);

        // 2. resolve pending children: poll own fragment + rsum word
        while (pend) {
            int done = 0;
#pragma unroll
            for (int j = 0; j < 6; ++j)
                if ((pend >> j) & 1) {
                    int r = pidx[j] - N_LEAVES;
                    F2U u; u.f = pv[j];
                    if (u.u == SENT8) { u.u = frag_load(P, r, lane); pv[j] = u.f; }
                    if (__float_as_uint(rs[j]) == SENT4)
                        rs[j] = __hip_atomic_load(&rsum[r], __ATOMIC_RELAXED, AGENT);
                    if (__all((u.u != SENT8) && (__float_as_uint(rs[j]) != SENT4)))
                        done |= 1 << j;
                }
            pend &= ~done;
            if (pend) __builtin_amdgcn_s_sleep(1);
        }

        // 3. leaf one-hots (species loads issued last iteration)
#pragma unroll
        for (int j = 0; j < 6; ++j)
            if ((leafm >> j) & 1) {
                pv[j].x = (sp6[j] == 2 * lane) ? 1.f : 0.f;
                pv[j].y = (sp6[j] == 2 * lane + 1) ? 1.f : 0.f;
                rs[j] = 1.f;
            }

        // 4. clade likelihood row
        float v0 = 0.f, v1 = 0.f;
#pragma unroll
        for (int jj = 0; jj < KSPLITS; ++jj) {
            float2 a = pv[jj], b = pv[jj + 3];
            float sl = rs[jj], sr = rs[jj + 3], w = wq[jj];
            v0 += w * (onepD * a.x * b.x + T127 * (a.x * (sr - b.x) + b.x * (sl - a.x)));
            v1 += w * (onepD * a.y * b.y + T127 * (a.y * (sr - b.y) + b.y * (sl - a.y)));
        }
        v0 /= denom;
        v1 /= denom;

        // 5. interleaved max + total reduction
        float mx = fmaxf(v0, v1);
        float tt = v0 + v1;
#pragma unroll
        for (int d = 1; d < 64; d <<= 1) {
            mx = fmaxf(mx, __shfl_xor(mx, d));
            tt += __shfl_xor(tt, d);
        }
        const float safe = fmaxf(mx, EPS);

        // 6. publish: fire-and-forget sc1 stores (8B fragment stores are
        //    single-copy atomic; no drain, no flag)
        const int row = k * WC + c;
        F2U o;
        o.f = make_float2(v0 / safe, v1 / safe);
        __hip_atomic_store((unsigned long long*)(P + (size_t)row * S) + lane,
                           o.u, __ATOMIC_RELAXED, AGENT);
        if (lane == 0) {
            __hip_atomic_store(&rsum[row], tt / safe, __ATOMIC_RELAXED, AGENT);
            __hip_atomic_store(&lsv[row], logf(safe), __ATOMIC_RELAXED, AGENT);
        }

        // 7. classify + issue next wave's gathers (rows < lo_{k+1}, possibly
        //    mid-publication by other wavefronts -> resolved next iteration)
        if (k + 1 < WAVES) {
            GATHER_CLASSIFY(k + 1, idxT, lwT, npv, nrs, nsp, npidx, nwq,
                            nleafm, npend);
#pragma unroll
            for (int j = 0; j < 6; ++j) {
                pv[j] = npv[j]; rs[j] = nrs[j]; sp6[j] = nsp[j]; pidx[j] = npidx[j];
            }
            wq[0] = nwq[0]; wq[1] = nwq[1]; wq[2] = nwq[2];
            leafm = nleafm; pend = npend;
        }
    }

    // final: per-family ll needs only rsum + ls of the root row. Leaf roots
    // contribute exactly 0 (log(1+1e-30)==0 in f32) — skipped bitwise.
    const int r = root_ids[c];
    if (r >= N_LEAVES && lane == 0) {
        const int row = r - N_LEAVES;
        float rv, lv;
        while (__float_as_uint(rv = __hip_atomic_load(&rsum[row], __ATOMIC_RELAXED,
                                                      AGENT)) == SENT4)
            __builtin_amdgcn_s_sleep(1);
        while (__float_as_uint(lv = __hip_atomic_load(&lsv[row], __ATOMIC_RELAXED,
                                                      AGENT)) == SENT4)
            __builtin_amdgcn_s_sleep(1);
        atomicAdd(out, -(logf(rv + EPS) + lv));
    }
}

// ---------------------------------------------------------------------------
extern "C" void kernel_launch(void* const* d_in, const int* in_sizes, int n_in,
                              void* d_out, int out_size, void* d_ws, size_t ws_size,
                              hipStream_t stream) {
    const float* theta        = (const float*)d_in[0];
    const float* logw         = (const float*)d_in[1];
    const int*   left         = (const int*)d_in[2];
    const int*   right        = (const int*)d_in[3];
    const int*   leaf_species = (const int*)d_in[4];
    const int*   root_ids     = (const int*)d_in[5];
    float* out = (float*)d_out;

    char* ws = (char*)d_ws;
    float* P    = (float*)ws;                                   // 49152*128*4 = 25.17 MB
    float* rsum = (float*)(ws + (size_t)N_INT * S * 4);         // 49152 floats
    float* lsv  = rsum + N_INT;                                 // 49152 floats

    init_kernel<<<2048, 256, 0, stream>>>((uint4*)P, (unsigned*)rsum,
                                          (unsigned*)lsv, out);
    fused_kernel<<<NBLK, TPB, 0, stream>>>(theta, logw, left, right,
                                           leaf_species, root_ids,
                                           P, rsum, lsv, out);
}